// Round 5
// baseline (231.902 us; speedup 1.0000x reference)
//
#include <hip/hip_runtime.h>
#include <math.h>

// WL1 loss over [B=16, C=3, H=512, W=512] fp32.
//   r = sum_c|hr-sr|/255 ; e = sum_c|hr-ema|/255
//   patch_w[b] = (unbiased var of r over sample)^0.2
//   pixel_w = unbiased 3x3 local var of r (reflect pad)
//   loss = mean(|w*sr - w*hr|) = (1/N) sum patch_w * pixel_w * mask * 255*r
//
// R5: latency-bound fix. Barrier-free, LDS-free wave-autonomous stencil.
// Wave = 256-col half x 4 output rows (6 r-rows incl. halo). Lane = 4 cols.
// Explicit issue/consume double-buffer: row n+1's 9 float4 loads in flight
// while row n converts+shfls+stencils (shfl at CONSUME time, not load time —
// R3's mistake). 4096 waves = 1024 blocks = 4 blocks/CU (launch_bounds 256,4).
// Horizontal halo via __shfl; half-boundary column via 1-lane scalar loads;
// image-edge reflect is in-register (col -1 -> own r.y, col 512 -> own r.z).

#define BB 16
#define HH 512
#define WW 512
#define HW (HH * WW)
#define CHW (3 * HW)
#define NREGIONS 4096
#define REG_PER_B 256
#define NBLOCKS 1024

__device__ __forceinline__ int reflect_h(int gh) {
  gh = gh < 0 ? -gh : gh;
  return gh >= HH ? 2 * HH - 2 - gh : gh;
}

struct Raw {
  float4 h0, h1, h2, s0, s1, s2;  // hr, sr (3 planes)
  float4 m0, m1, m2;              // ema (center rows only)
  float eh0, eh1, eh2, es0, es1, es2;  // edge column scalars (1 lane)
};

__device__ __forceinline__ void issue_row(Raw& R, int n, bool withE,
                                          const float* __restrict__ hrb,
                                          const float* __restrict__ srb,
                                          const float* __restrict__ emb,
                                          int col, int ecol, bool edge_lane) {
  const int gh = reflect_h(n);
  const float* hp = hrb + gh * WW + col;
  const float* sp = srb + gh * WW + col;
  R.h0 = *(const float4*)hp;
  R.h1 = *(const float4*)(hp + HW);
  R.h2 = *(const float4*)(hp + 2 * HW);
  R.s0 = *(const float4*)sp;
  R.s1 = *(const float4*)(sp + HW);
  R.s2 = *(const float4*)(sp + 2 * HW);
  if (withE) {
    const float* mp = emb + gh * WW + col;
    R.m0 = *(const float4*)mp;
    R.m1 = *(const float4*)(mp + HW);
    R.m2 = *(const float4*)(mp + 2 * HW);
  }
  if (edge_lane) {
    const float* hq = hrb + gh * WW + ecol;
    const float* sq = srb + gh * WW + ecol;
    R.eh0 = hq[0]; R.eh1 = hq[HW]; R.eh2 = hq[2 * HW];
    R.es0 = sq[0]; R.es1 = sq[HW]; R.es2 = sq[2 * HW];
  }
}

// Convert raw -> r row (6-wide incl. neighbors) and premasked f (center rows).
__device__ __forceinline__ void consume_row(const Raw& R, bool withE,
                                            bool half1, int lane, float* v6,
                                            float4* f4out) {
  float4 r;
  r.x = (fabsf(R.h0.x - R.s0.x) + fabsf(R.h1.x - R.s1.x) + fabsf(R.h2.x - R.s2.x)) / 255.0f;
  r.y = (fabsf(R.h0.y - R.s0.y) + fabsf(R.h1.y - R.s1.y) + fabsf(R.h2.y - R.s2.y)) / 255.0f;
  r.z = (fabsf(R.h0.z - R.s0.z) + fabsf(R.h1.z - R.s1.z) + fabsf(R.h2.z - R.s2.z)) / 255.0f;
  r.w = (fabsf(R.h0.w - R.s0.w) + fabsf(R.h1.w - R.s1.w) + fabsf(R.h2.w - R.s2.w)) / 255.0f;
  // edge-column r (valid only on the edge lane; selected below)
  float er = (fabsf(R.eh0 - R.es0) + fabsf(R.eh1 - R.es1) + fabsf(R.eh2 - R.es2)) / 255.0f;
  float lvs = __shfl_up(r.w, 1, 64);
  float rvs = __shfl_down(r.x, 1, 64);
  float lv, rv;
  if (half1) {  // cols 256..511: left boundary needs col 255; right edge reflects to own col 510 (r.z)
    lv = (lane == 0) ? er : lvs;
    rv = (lane == 63) ? r.z : rvs;
  } else {  // cols 0..255: left edge reflects to own col 1 (r.y); right boundary needs col 256
    lv = (lane == 0) ? r.y : lvs;
    rv = (lane == 63) ? er : rvs;
  }
  v6[0] = lv; v6[1] = r.x; v6[2] = r.y; v6[3] = r.z; v6[4] = r.w; v6[5] = rv;
  if (withE) {
    float4 e;
    e.x = (fabsf(R.h0.x - R.m0.x) + fabsf(R.h1.x - R.m1.x) + fabsf(R.h2.x - R.m2.x)) / 255.0f;
    e.y = (fabsf(R.h0.y - R.m0.y) + fabsf(R.h1.y - R.m1.y) + fabsf(R.h2.y - R.m2.y)) / 255.0f;
    e.z = (fabsf(R.h0.z - R.m0.z) + fabsf(R.h1.z - R.m1.z) + fabsf(R.h2.z - R.m2.z)) / 255.0f;
    e.w = (fabsf(R.h0.w - R.m0.w) + fabsf(R.h1.w - R.m1.w) + fabsf(R.h2.w - R.m2.w)) / 255.0f;
    f4out->x = (r.x >= e.x) ? 255.0f * r.x : 0.0f;
    f4out->y = (r.y >= e.y) ? 255.0f * r.y : 0.0f;
    f4out->z = (r.z >= e.z) ? 255.0f * r.z : 0.0f;
    f4out->w = (r.w >= e.w) ? 255.0f * r.w : 0.0f;
  }
}

__device__ __forceinline__ void stencil(const float* rU, const float* rM,
                                        const float* rD, const float4 f,
                                        float& v1, float& v2, float& v3) {
  float cs[6], cq[6];
#pragma unroll
  for (int j = 0; j < 6; ++j) {
    cs[j] = rU[j] + rM[j] + rD[j];
    cq[j] = rU[j] * rU[j] + rM[j] * rM[j] + rD[j] * rD[j];
  }
  const float fv[4] = {f.x, f.y, f.z, f.w};
#pragma unroll
  for (int c = 0; c < 4; ++c) {
    float s = cs[c] + cs[c + 1] + cs[c + 2];
    float q = cq[c] + cq[c + 1] + cq[c + 2];
    float pvar = (q - s * s / 9.0f) / 8.0f;
    float rc = rM[c + 1];
    v1 += rc;
    v2 += rc * rc;
    v3 += pvar * fv[c];
  }
}

__global__ __launch_bounds__(256, 4) void wl1_main(
    const float* __restrict__ sr, const float* __restrict__ srema,
    const float* __restrict__ hr, float* __restrict__ p_sum,
    float* __restrict__ p_sum2, float* __restrict__ p_loss) {
  const int tid = threadIdx.x;
  const int lane = tid & 63;
  const int region = blockIdx.x * 4 + (tid >> 6);
  const int b = region >> 8;
  const int rem = region & 255;
  const int half = rem & 1;
  const int h0 = (rem >> 1) << 2;  // 0..508
  const int w0 = half << 8;
  const float* __restrict__ srb = sr + (size_t)b * CHW;
  const float* __restrict__ hrb = hr + (size_t)b * CHW;
  const float* __restrict__ emb = srema + (size_t)b * CHW;
  const int col = w0 + 4 * lane;
  const bool half1 = (half != 0);
  const int ecol = half1 ? 255 : 256;          // half-boundary neighbor column
  const bool edge_lane = half1 ? (lane == 0) : (lane == 63);

  Raw A, B;
  float r0[6], r1[6], r2[6], r3[6], r4[6], r5[6];
  float4 f0, f1, f2, f3, fd;
  float v1 = 0.f, v2 = 0.f, v3 = 0.f;

  issue_row(A, h0 - 1, false, hrb, srb, emb, col, ecol, edge_lane);
  issue_row(B, h0 + 0, true, hrb, srb, emb, col, ecol, edge_lane);
  consume_row(A, false, half1, lane, r0, &fd);          // row -1 (B in flight)
  issue_row(A, h0 + 1, true, hrb, srb, emb, col, ecol, edge_lane);
  consume_row(B, true, half1, lane, r1, &f0);           // row 0 (A in flight)
  issue_row(B, h0 + 2, true, hrb, srb, emb, col, ecol, edge_lane);
  consume_row(A, true, half1, lane, r2, &f1);           // row 1 (B in flight)
  stencil(r0, r1, r2, f0, v1, v2, v3);                  // orow 0
  issue_row(A, h0 + 3, true, hrb, srb, emb, col, ecol, edge_lane);
  consume_row(B, true, half1, lane, r3, &f2);           // row 2 (A in flight)
  stencil(r1, r2, r3, f1, v1, v2, v3);                  // orow 1
  issue_row(B, h0 + 4, false, hrb, srb, emb, col, ecol, edge_lane);
  consume_row(A, true, half1, lane, r4, &f3);           // row 3 (B in flight)
  stencil(r2, r3, r4, f2, v1, v2, v3);                  // orow 2
  consume_row(B, false, half1, lane, r5, &fd);          // row 4
  stencil(r3, r4, r5, f3, v1, v2, v3);                  // orow 3

  // wave reduce -> one partial triple per region (v1 also fixes patch var)
#pragma unroll
  for (int off = 32; off > 0; off >>= 1) {
    v1 += __shfl_down(v1, off, 64);
    v2 += __shfl_down(v2, off, 64);
    v3 += __shfl_down(v3, off, 64);
  }
  if (lane == 0) {
    p_sum[region] = v1;
    p_sum2[region] = v2;
    p_loss[region] = v3;
  }
}

// One 1024-thread block: wave b folds batch b's 256 region partials.
__global__ __launch_bounds__(1024) void wl1_reduce(
    const float* __restrict__ p_sum, const float* __restrict__ p_sum2,
    const float* __restrict__ p_loss, float* __restrict__ out) {
  const int tid = threadIdx.x;
  const int b = tid >> 6, k = tid & 63;
  double s = 0.0, s2 = 0.0, sl = 0.0;
#pragma unroll
  for (int j = 0; j < REG_PER_B; j += 64) {
    int i = b * REG_PER_B + j + k;
    s += (double)p_sum[i];
    s2 += (double)p_sum2[i];
    sl += (double)p_loss[i];
  }
#pragma unroll
  for (int off = 32; off > 0; off >>= 1) {
    s += __shfl_down(s, off, 64);
    s2 += __shfl_down(s2, off, 64);
    sl += __shfl_down(sl, off, 64);
  }
  __shared__ double acc[BB];
  if (k == 0) {
    const double n = (double)HW;
    double var = (s2 - s * s / n) / (n - 1.0);
    acc[b] = pow(var, 0.2) * sl;
  }
  __syncthreads();
  if (tid == 0) {
    double tot = 0.0;
#pragma unroll
    for (int j = 0; j < BB; ++j) tot += acc[j];
    out[0] = (float)(tot / (double)((size_t)BB * CHW));
  }
}

extern "C" void kernel_launch(void* const* d_in, const int* in_sizes, int n_in,
                              void* d_out, int out_size, void* d_ws,
                              size_t ws_size, hipStream_t stream) {
  const float* sr = (const float*)d_in[0];
  const float* srema = (const float*)d_in[1];
  const float* hr = (const float*)d_in[2];
  float* out = (float*)d_out;

  float* p_sum = (float*)d_ws;
  float* p_sum2 = p_sum + NREGIONS;
  float* p_loss = p_sum2 + NREGIONS;

  wl1_main<<<NBLOCKS, 256, 0, stream>>>(sr, srema, hr, p_sum, p_sum2, p_loss);
  wl1_reduce<<<1, 1024, 0, stream>>>(p_sum, p_sum2, p_loss, out);
}

// Round 6
// 172.376 us; speedup vs baseline: 1.3453x; 1.3453x over previous
//
#include <hip/hip_runtime.h>
#include <math.h>

// WL1 loss over [B=16, C=3, H=512, W=512] fp32.
//   r = sum_c|hr-sr|/255 ; e = sum_c|hr-ema|/255
//   patch_w[b] = (unbiased var of r over sample)^0.2
//   pixel_w = unbiased 3x3 local var of r (reflect pad)
//   loss = mean(|w*sr - w*hr|) = (1/N) sum patch_w * pixel_w * mask * 255*r
//
// R6: split streaming from stenciling.
// Pass 1 (copy-shaped, no LDS/barriers): linear float4 sweep, 9 loads +
//   1 store/thread; writes rf = (r<e ? -r : r)  (mask in sign bit; r>=0),
//   one compact 16 MiB array; accumulates v1=sum r, v2=sum r^2 per block.
// Pass 2: 3x3 stencil over compact rf (25 MB, L2/L3-hot), R4 LDS structure,
//   accumulates v3 = sum pixel_var * (masked 255 r).
// Pass 3: fold partials, patch_w = var^0.2, final scalar.

#define BB 16
#define HH 512
#define WW 512
#define HW (HH * WW)
#define CHW (3 * HW)
#define GRP_PER_B (HW / 4)          // 65536 float4 groups per image
#define NGRP (BB * GRP_PER_B)       // 1,048,576
#define P1_BLOCKS (NGRP / 256)      // 4096 (256 per batch)
#define P1_PER_B 256
#define STRIPS 128                  // 512 rows / 4
#define P2_BLOCKS (BB * STRIPS)     // 2048
#define P2_PER_B STRIPS

__device__ __forceinline__ int reflect_h(int gh) {
  gh = gh < 0 ? -gh : gh;
  return gh >= HH ? 2 * HH - 2 - gh : gh;
}

// ---------------- Pass 1: streaming residual + mask + patch sums ----------
__global__ __launch_bounds__(256) void wl1_pass1(
    const float* __restrict__ sr, const float* __restrict__ srema,
    const float* __restrict__ hr, float4* __restrict__ rfbuf,
    float* __restrict__ p_sum, float* __restrict__ p_sum2) {
  const int tid = threadIdx.x;
  const int g = blockIdx.x * 256 + tid;          // float4 group index
  const int b = g >> 16;                          // g / GRP_PER_B
  const int pix = g & 65535;
  const float* __restrict__ sp = sr + (size_t)b * CHW + 4 * pix;
  const float* __restrict__ hp = hr + (size_t)b * CHW + 4 * pix;
  const float* __restrict__ mp = srema + (size_t)b * CHW + 4 * pix;

  float4 s0 = *(const float4*)sp;
  float4 s1 = *(const float4*)(sp + HW);
  float4 s2 = *(const float4*)(sp + 2 * HW);
  float4 h0 = *(const float4*)hp;
  float4 h1 = *(const float4*)(hp + HW);
  float4 h2 = *(const float4*)(hp + 2 * HW);
  float4 m0 = *(const float4*)mp;
  float4 m1 = *(const float4*)(mp + HW);
  float4 m2 = *(const float4*)(mp + 2 * HW);

  float4 r4, e4, o4;
  r4.x = (fabsf(h0.x - s0.x) + fabsf(h1.x - s1.x) + fabsf(h2.x - s2.x)) / 255.0f;
  r4.y = (fabsf(h0.y - s0.y) + fabsf(h1.y - s1.y) + fabsf(h2.y - s2.y)) / 255.0f;
  r4.z = (fabsf(h0.z - s0.z) + fabsf(h1.z - s1.z) + fabsf(h2.z - s2.z)) / 255.0f;
  r4.w = (fabsf(h0.w - s0.w) + fabsf(h1.w - s1.w) + fabsf(h2.w - s2.w)) / 255.0f;
  e4.x = (fabsf(h0.x - m0.x) + fabsf(h1.x - m1.x) + fabsf(h2.x - m2.x)) / 255.0f;
  e4.y = (fabsf(h0.y - m0.y) + fabsf(h1.y - m1.y) + fabsf(h2.y - m2.y)) / 255.0f;
  e4.z = (fabsf(h0.z - m0.z) + fabsf(h1.z - m1.z) + fabsf(h2.z - m2.z)) / 255.0f;
  e4.w = (fabsf(h0.w - m0.w) + fabsf(h1.w - m1.w) + fabsf(h2.w - m2.w)) / 255.0f;
  // mask (r < e) encoded in sign bit; r >= 0 so sign is free
  o4.x = (r4.x < e4.x) ? -r4.x : r4.x;
  o4.y = (r4.y < e4.y) ? -r4.y : r4.y;
  o4.z = (r4.z < e4.z) ? -r4.z : r4.z;
  o4.w = (r4.w < e4.w) ? -r4.w : r4.w;
  rfbuf[g] = o4;

  float v1 = r4.x + r4.y + r4.z + r4.w;
  float v2 = r4.x * r4.x + r4.y * r4.y + r4.z * r4.z + r4.w * r4.w;
#pragma unroll
  for (int off = 32; off > 0; off >>= 1) {
    v1 += __shfl_down(v1, off, 64);
    v2 += __shfl_down(v2, off, 64);
  }
  __shared__ float red[2][4];
  const int wave = tid >> 6, lane = tid & 63;
  if (lane == 0) { red[0][wave] = v1; red[1][wave] = v2; }
  __syncthreads();
  if (tid == 0) {
    p_sum[blockIdx.x] = red[0][0] + red[0][1] + red[0][2] + red[0][3];
    p_sum2[blockIdx.x] = red[1][0] + red[1][1] + red[1][2] + red[1][3];
  }
}

// ---------------- Pass 2: 3x3 stencil over compact rf --------------------
__global__ __launch_bounds__(256, 8) void wl1_pass2(
    const float4* __restrict__ rfbuf, float* __restrict__ p_loss) {
  __shared__ float rt[6][WW];  // |rf| for halo rows h0-1 .. h0+4
  __shared__ float ft[4][WW];  // premasked 255*r for center rows
  const int tid = threadIdx.x;
  const int bid = blockIdx.x;
  const int b = bid >> 7;
  const int h0 = (bid & 127) << 2;

  // Stage A: 6 rows x 128 float4 groups = 768 items, 3 clean passes.
#pragma unroll
  for (int it = 0; it < 3; ++it) {
    const int item = it * 256 + tid;
    const int row = item >> 7;  // 0..5 (wave-uniform)
    const int g = item & 127;
    const int gh = reflect_h(h0 - 1 + row);
    float4 v = rfbuf[(b << 16) + gh * 128 + g];
    float4 a4;
    a4.x = fabsf(v.x); a4.y = fabsf(v.y); a4.z = fabsf(v.z); a4.w = fabsf(v.w);
    *(float4*)&rt[row][4 * g] = a4;
    if (row >= 1 && row <= 4) {
      float4 f4;
      f4.x = (__float_as_uint(v.x) >> 31) ? 0.0f : 255.0f * a4.x;
      f4.y = (__float_as_uint(v.y) >> 31) ? 0.0f : 255.0f * a4.y;
      f4.z = (__float_as_uint(v.z) >> 31) ? 0.0f : 255.0f * a4.z;
      f4.w = (__float_as_uint(v.w) >> 31) ? 0.0f : 255.0f * a4.w;
      *(float4*)&ft[row - 1][4 * g] = f4;
    }
  }
  __syncthreads();

  // Stage B: pure LDS. Thread -> output rows {r0, r0+2}, float4 group g.
  const int g = tid & 127;
  const int r0 = tid >> 7;  // 0 or 1
  const int li = (g == 0) ? 1 : 4 * g - 1;
  const int ri = (g == 127) ? 510 : 4 * g + 4;
  float v3 = 0.f;
#pragma unroll
  for (int k = 0; k < 2; ++k) {
    const int orow = r0 + 2 * k;  // output row within strip (0..3)
    float cs[6] = {0, 0, 0, 0, 0, 0}, cq[6] = {0, 0, 0, 0, 0, 0};
#pragma unroll
    for (int dr = 0; dr < 3; ++dr) {
      const int row = orow + dr;
      float4 c4 = *(const float4*)&rt[row][4 * g];
      float lv = rt[row][li];
      float rv = rt[row][ri];
      float v[6] = {lv, c4.x, c4.y, c4.z, c4.w, rv};
#pragma unroll
      for (int j = 0; j < 6; ++j) {
        cs[j] += v[j];
        cq[j] += v[j] * v[j];
      }
    }
    float4 f4 = *(const float4*)&ft[orow][4 * g];
    const float fv[4] = {f4.x, f4.y, f4.z, f4.w};
#pragma unroll
    for (int c = 0; c < 4; ++c) {
      float s = cs[c] + cs[c + 1] + cs[c + 2];
      float q = cq[c] + cq[c + 1] + cq[c + 2];
      float pvar = (q - s * s / 9.0f) / 8.0f;
      v3 += pvar * fv[c];
    }
  }

#pragma unroll
  for (int off = 32; off > 0; off >>= 1) v3 += __shfl_down(v3, off, 64);
  __syncthreads();  // stage-B reads done before LDS reuse
  const int wave = tid >> 6, lane = tid & 63;
  if (lane == 0) rt[0][wave] = v3;
  __syncthreads();
  if (tid == 0) p_loss[bid] = rt[0][0] + rt[0][1] + rt[0][2] + rt[0][3];
}

// ---------------- Pass 3: fold partials ----------------------------------
__global__ __launch_bounds__(1024) void wl1_reduce(
    const float* __restrict__ p_sum, const float* __restrict__ p_sum2,
    const float* __restrict__ p_loss, float* __restrict__ out) {
  const int tid = threadIdx.x;
  const int b = tid >> 6, k = tid & 63;
  double s = 0.0, s2 = 0.0, sl = 0.0;
#pragma unroll
  for (int j = 0; j < P1_PER_B; j += 64) {
    int i = b * P1_PER_B + j + k;
    s += (double)p_sum[i];
    s2 += (double)p_sum2[i];
  }
#pragma unroll
  for (int j = 0; j < P2_PER_B; j += 64) {
    sl += (double)p_loss[b * P2_PER_B + j + k];
  }
#pragma unroll
  for (int off = 32; off > 0; off >>= 1) {
    s += __shfl_down(s, off, 64);
    s2 += __shfl_down(s2, off, 64);
    sl += __shfl_down(sl, off, 64);
  }
  __shared__ double acc[BB];
  if (k == 0) {
    const double n = (double)HW;
    double var = (s2 - s * s / n) / (n - 1.0);
    acc[b] = pow(var, 0.2) * sl;
  }
  __syncthreads();
  if (tid == 0) {
    double tot = 0.0;
#pragma unroll
    for (int j = 0; j < BB; ++j) tot += acc[j];
    out[0] = (float)(tot / (double)((size_t)BB * CHW));
  }
}

extern "C" void kernel_launch(void* const* d_in, const int* in_sizes, int n_in,
                              void* d_out, int out_size, void* d_ws,
                              size_t ws_size, hipStream_t stream) {
  const float* sr = (const float*)d_in[0];
  const float* srema = (const float*)d_in[1];
  const float* hr = (const float*)d_in[2];
  float* out = (float*)d_out;

  // ws layout: rfbuf (16 MiB) | p_sum (4096) | p_sum2 (4096) | p_loss (2048)
  float4* rfbuf = (float4*)d_ws;
  float* p_sum = (float*)((char*)d_ws + (size_t)NGRP * sizeof(float4));
  float* p_sum2 = p_sum + P1_BLOCKS;
  float* p_loss = p_sum2 + P1_BLOCKS;

  wl1_pass1<<<P1_BLOCKS, 256, 0, stream>>>(sr, srema, hr, rfbuf, p_sum, p_sum2);
  wl1_pass2<<<P2_BLOCKS, 256, 0, stream>>>(rfbuf, p_loss);
  wl1_reduce<<<1, 1024, 0, stream>>>(p_sum, p_sum2, p_loss, out);
}